// Round 11
// baseline (741.185 us; speedup 1.0000x reference)
//
#include <hip/hip_runtime.h>
#include <math.h>

// VectorQuantizer: argmin_k ||x_n - c_k||^2, N=32768, K=8192, D=64, fp32.
// Round-11: 2 waves/SIMD. Round-10 (1 wave/SIMD, barrier-free) proved a lone
// wave serializes its VALU (epilogue/addressing, ~1000 cyc/tile) behind its
// own MFMA issue (775 cyc/tile pipe floor) -> 2344 cyc/tile. Fix: 128-thr
// blocks (2 waves, each owning a private 32-row C-tile), BTILE=32, ksplit=2
// -> grid 1024 = 4 blocks/CU (37.6 KB LDS) = 8 waves/CU = 2/SIMD: partner
// waves' MFMA hides our VALU, and 4 independent blocks/CU decorrelate the
// per-tile 2-wave barrier (r7's convoy was 4-wave at only 2 blocks/CU).
// DMA: the wave PAIR splits the 13 chunks 7/6 (global_load_lds), each wave
// waits its OWN vmcnt (asm-fenced) then s_barrier -> both waves' chunks
// landed (r7-proven scheme). K split in 2 segments; per-seg winner written
// as monotone-transformed u64 key (r10's sign fix) to scratch; tiny reduce
// kernel takes the min (ascending segs + embedded code = numpy
// first-occurrence preserved).
// Numerics: identical to r10 (passed, absmax 0): 3-plane bf16 split, 6 MFMA
// products in 4 chains, dist' = csq - 2*dot (xsq argmin-invariant), strict <
// ascending code, u64 key mins.

typedef __attribute__((ext_vector_type(8)))  short s8v;
typedef __attribute__((ext_vector_type(16))) float f16v;

constexpr int NROWS = 32768;
constexpr int KC    = 8192;
constexpr int DD    = 64;
constexpr int TPB   = 128;           // 2 waves
constexpr int BROWS = 64;            // rows per block (32 per wave)
constexpr int BTILE = 32;            // codes per tile
constexpr int NTILES_ALL = KC / BTILE;   // 256
constexpr int KSPLIT = 2;
constexpr int NT_SEG = NTILES_ALL / KSPLIT;  // 128 tiles per segment
constexpr int TSH     = 6272;        // shorts/tile: 6144 planes + 64 csq + 64 pad
constexpr int CSQ_OFF = 6144;

__device__ __forceinline__ short bf16_rne(float v, float& resid) {
  unsigned u = __float_as_uint(v);
  unsigned r = (u + 0x7FFFu + ((u >> 16) & 1u)) >> 16;
  resid = v - __uint_as_float(r << 16);   // exact
  return (short)r;
}
__device__ __forceinline__ void split3(float v, short& b1, short& b2, short& b3) {
  float r1, r2, r3;
  b1 = bf16_rne(v, r1);
  b2 = bf16_rne(r1, r2);
  b3 = bf16_rne(r2, r3);
}

__device__ __forceinline__ void dma16(const short* g, short* l) {
  __builtin_amdgcn_global_load_lds(
      (const __attribute__((address_space(1))) unsigned int*)g,
      (__attribute__((address_space(3))) unsigned int*)l, 16, 0, 0);
}
__device__ __forceinline__ void dma4(const short* g, short* l) {
  __builtin_amdgcn_global_load_lds(
      (const __attribute__((address_space(1))) unsigned int*)g,
      (__attribute__((address_space(3))) unsigned int*)l, 4, 0, 0);
}

// Pre-kernel (unchanged from r10, proven): one 64-thr block per 32-code
// group; coalesced load to LDS, split3 to the 12 frag-ordered chunks +
// embedded csq (sequential fmaf chain, same as all passing rounds).
__global__ __launch_bounds__(64)
void vq_pre_kernel(const float* __restrict__ cb, short* __restrict__ bSwz) {
  __shared__ float st[BTILE][65];
  const int g = blockIdx.x;
  const int lane = threadIdx.x;

  const float4* src = (const float4*)(cb + (size_t)g * BTILE * DD);
#pragma unroll
  for (int i = 0; i < 8; ++i) {
    const int f = i * 64 + lane;
    const float4 v = src[f];
    const int row = f >> 4, c0 = (f & 15) * 4;
    st[row][c0] = v.x; st[row][c0 + 1] = v.y;
    st[row][c0 + 2] = v.z; st[row][c0 + 3] = v.w;
  }
  __syncthreads();

  const int code = lane & 31, half = lane >> 5;
  short* base = bSwz + (size_t)g * TSH;
#pragma unroll
  for (int kc = 0; kc < 4; ++kc) {
    s8v p1, p2, p3;
#pragma unroll
    for (int j = 0; j < 8; ++j) {
      short a, b, c;
      split3(st[code][kc * 16 + half * 8 + j], a, b, c);
      p1[j] = a; p2[j] = b; p3[j] = c;
    }
    *(s8v*)(base + (0 * 4 + kc) * 512 + lane * 8) = p1;
    *(s8v*)(base + (1 * 4 + kc) * 512 + lane * 8) = p2;
    *(s8v*)(base + (2 * 4 + kc) * 512 + lane * 8) = p3;
  }
  if (lane < BTILE) {
    float s = 0.f;
#pragma unroll
    for (int d = 0; d < DD; ++d) s = fmaf(st[lane][d], st[lane][d], s);
    ((float*)(base + CSQ_OFF))[lane] = s;
  }
}

__global__ __launch_bounds__(TPB) __attribute__((amdgpu_waves_per_eu(2)))
void vq_mfma_kernel(const float* __restrict__ x, const short* __restrict__ bSwz,
                    unsigned long long* __restrict__ segKey) {
  __shared__ alignas(16) short ldsB[3][TSH];   // 37,632 B -> 4 blocks/CU

  const int tid  = threadIdx.x;
  const int lane = tid & 63;
  const int w    = tid >> 6;           // wave 0/1
  const int col  = lane & 31;
  const int half = lane >> 5;
  const int seg  = blockIdx.y;
  const int blockRow = blockIdx.x * BROWS + w * 32;   // wave-private 32 rows

  // ---- A fragments from global, split once: row = blockRow + col.
  s8v afr[3][4];
  {
    const float* xr = x + (size_t)(blockRow + col) * DD;
#pragma unroll
    for (int kc = 0; kc < 4; ++kc) {
      const float* p8 = xr + kc * 16 + half * 8;
      const float4 a = *(const float4*)p8;
      const float4 b = *(const float4*)(p8 + 4);
      const float v[8] = {a.x, a.y, a.z, a.w, b.x, b.y, b.z, b.w};
      s8v q1, q2, q3;
#pragma unroll
      for (int e = 0; e < 8; ++e) {
        short t1, t2, t3; split3(v[e], t1, t2, t3);
        q1[e] = t1; q2[e] = t2; q3[e] = t3;
      }
      afr[0][kc] = q1; afr[1][kc] = q2; afr[2][kc] = q3;
    }
  }

  short* b0 = &ldsB[0][0];
  short* b1 = &ldsB[1][0];
  short* b2 = &ldsB[2][0];

  const short* segBase = bSwz + (size_t)seg * NT_SEG * TSH;

  // The wave PAIR splits the tile's 13 chunks: w0 = chunks 0-5 + csq (7
  // issues), w1 = chunks 6-11 (6 issues). Own-vmcnt + barrier = landed.
  auto issue_tile = [&](int tl, short* buf) {
    const short* g = segBase + (size_t)tl * TSH;
    if (w == 0) {
#pragma unroll
      for (int c = 0; c < 6; ++c)
        dma16(g + c * 512 + lane * 8, buf + c * 512 + lane * 8);
      dma4(g + CSQ_OFF + lane * 2, buf + CSQ_OFF + lane * 2);
    } else {
#pragma unroll
      for (int c = 6; c < 12; ++c)
        dma16(g + c * 512 + lane * 8, buf + c * 512 + lane * 8);
    }
  };

  issue_tile(0, b0);
  issue_tile(1, b1);

  const f16v zero16 = {0.f,0.f,0.f,0.f,0.f,0.f,0.f,0.f,
                       0.f,0.f,0.f,0.f,0.f,0.f,0.f,0.f};
  const f16v neg16  = {-1e30f,-1e30f,-1e30f,-1e30f,-1e30f,-1e30f,-1e30f,-1e30f,
                       -1e30f,-1e30f,-1e30f,-1e30f,-1e30f,-1e30f,-1e30f,-1e30f};
  f16v S0[4], S1[4];
#pragma unroll
  for (int i = 0; i < 4; ++i) { S0[i] = zero16; S1[i] = neg16; }
  float csOld = 0.f;
  float bestD[16];
  unsigned bestC[16];
#pragma unroll
  for (int i = 0; i < 16; ++i) { bestD[i] = __builtin_inff(); bestC[i] = 0u; }

  constexpr int PAA[3] = {0, 1, 1}, PBA[3] = {0, 0, 1};
  constexpr int PAB[3] = {0, 0, 2}, PBB[3] = {1, 2, 0};

  // Tile body: [own-vmcnt wait (fenced)][s_barrier][frag ds_reads]
  // [24 MFMA into W][DMA t+2][pipelined epi(t-1) from R].
  // Outstanding at wait: 2 tiles x own issues (14 | 12) -> vmcnt(7 | 6).
  auto body = [&](int t, short* bufR, short* bufW, f16v* W, const f16v* R) {
    if (w == 0) asm volatile("s_waitcnt vmcnt(7)" ::: "memory");
    else        asm volatile("s_waitcnt vmcnt(6)" ::: "memory");
    __builtin_amdgcn_s_barrier();

    const float csNew = ((const float*)(bufR + CSQ_OFF))[col];
    s8v f[3][4];
#pragma unroll
    for (int p = 0; p < 3; ++p)
#pragma unroll
      for (int kc = 0; kc < 4; ++kc)
        f[p][kc] = *(const s8v*)(bufR + (p * 4 + kc) * 512 + lane * 8);

#pragma unroll
    for (int i = 0; i < 4; ++i) W[i] = zero16;
#pragma unroll
    for (int u = 0; u < 2; ++u)
#pragma unroll
      for (int pr = 0; pr < 3; ++pr) {
        W[0] = __builtin_amdgcn_mfma_f32_32x32x16_bf16(
            afr[PAA[pr]][u],     f[PBA[pr]][u],     W[0], 0, 0, 0);
        W[1] = __builtin_amdgcn_mfma_f32_32x32x16_bf16(
            afr[PAA[pr]][2 + u], f[PBA[pr]][2 + u], W[1], 0, 0, 0);
        W[2] = __builtin_amdgcn_mfma_f32_32x32x16_bf16(
            afr[PAB[pr]][u],     f[PBB[pr]][u],     W[2], 0, 0, 0);
        W[3] = __builtin_amdgcn_mfma_f32_32x32x16_bf16(
            afr[PAB[pr]][2 + u], f[PBB[pr]][2 + u], W[3], 0, 0, 0);
      }

    issue_tile((t + 2) & (NT_SEG - 1), bufW);   // wrap keeps FIFO uniform

    // Epilogue for tile t-1 (t=0: R=-1e30 -> dist ~ +8e30, never kept).
    const unsigned codeBase =
        (unsigned)(seg * (KC / KSPLIT) + (t - 1) * BTILE + col);
#pragma unroll
    for (int i = 0; i < 16; ++i) {
      const float acc = (R[0][i] + R[1][i]) + (R[2][i] + R[3][i]);
      const float dist = fmaf(-2.f, acc, csOld);   // may be negative
      if (dist < bestD[i]) { bestD[i] = dist; bestC[i] = codeBase; }
    }
    csOld = csNew;
  };

  for (int t = 0; t < NT_SEG; t += 2) {
    body(t, b0, b2, S0, S1);
    short* tmp0 = b0; b0 = b1; b1 = b2; b2 = tmp0;
    body(t + 1, b0, b2, S1, S0);
    short* tmp1 = b0; b0 = b1; b1 = b2; b2 = tmp1;
  }
  {
    const unsigned codeBase =
        (unsigned)(seg * (KC / KSPLIT) + (NT_SEG - 1) * BTILE + col);
#pragma unroll
    for (int i = 0; i < 16; ++i) {
      const float acc = (S1[0][i] + S1[1][i]) + (S1[2][i] + S1[3][i]);
      const float dist = fmaf(-2.f, acc, csOld);
      if (dist < bestD[i]) { bestD[i] = dist; bestC[i] = codeBase; }
    }
  }

  // Drain wrap-around DMAs before exit.
  asm volatile("s_waitcnt vmcnt(0)" ::: "memory");

  // ---- Cross-lane reduce with the monotone float->uint transform (dist
  // may be negative; r10's fix). Equal dists -> equal keys -> u64 min picks
  // the lowest code = numpy first-occurrence.
  unsigned long long key[16];
#pragma unroll
  for (int i = 0; i < 16; ++i) {
    unsigned sb = __float_as_uint(bestD[i]);
    sb = (sb & 0x80000000u) ? ~sb : (sb | 0x80000000u);
    key[i] = ((unsigned long long)sb << 32) | bestC[i];
  }
#pragma unroll
  for (int i = 0; i < 16; ++i) {
#pragma unroll
    for (int m = 1; m < 32; m <<= 1) {
      const unsigned long long o = __shfl_xor(key[i], m, 64);
      if (o < key[i]) key[i] = o;
    }
  }
  if (col == 0) {
#pragma unroll
    for (int i = 0; i < 16; ++i) {
      const int row = (i & 3) + 8 * (i >> 2) + 4 * half;
      segKey[(size_t)seg * NROWS + blockRow + row] = key[i];
    }
  }
}

__global__ __launch_bounds__(256)
void vq_reduce_kernel(const unsigned long long* __restrict__ segKey,
                      int* __restrict__ out) {
  const int n = blockIdx.x * blockDim.x + threadIdx.x;
  const unsigned long long a = segKey[n];
  const unsigned long long b = segKey[(size_t)NROWS + n];
  out[n] = (int)(unsigned)((a < b ? a : b) & 0xFFFFFFFFull);
}

extern "C" void kernel_launch(void* const* d_in, const int* in_sizes, int n_in,
                              void* d_out, int out_size, void* d_ws, size_t ws_size,
                              hipStream_t stream) {
  const float* x  = (const float*)d_in[0];   // [N, 64] fp32
  const float* cb = (const float*)d_in[1];   // [K, 64] fp32
  int* out = (int*)d_out;                    // [N] int32

  // ws: bSwz (256 x 12,544 B = 3.06 MB) | segKey (2 x 32768 x 8 B = 512 KB)
  short* bSwz = (short*)d_ws;
  unsigned long long* segKey =
      (unsigned long long*)((char*)d_ws + (size_t)NTILES_ALL * TSH * 2);

  vq_pre_kernel<<<dim3(NTILES_ALL), dim3(64), 0, stream>>>(cb, bSwz);
  vq_mfma_kernel<<<dim3(NROWS / BROWS, KSPLIT), dim3(TPB), 0, stream>>>(
      x, bSwz, segKey);
  vq_reduce_kernel<<<dim3(NROWS / 256), dim3(256), 0, stream>>>(segKey, out);
}